// Round 1
// baseline (668.776 us; speedup 1.0000x reference)
//
#include <hip/hip_runtime.h>
#include <math.h>

#define N 4096
#define NFEAT 512
#define NHID 64
#define NHEADS 8
#define P_PAIRS 65536
#define CAP 128
#define LRELU_ALPHA 0.2f

// ---------------- K1: build CSR from dense adj (one pass over 67 MB) -------
__global__ __launch_bounds__(256) void build_csr(const float* __restrict__ adj,
                                                 int* __restrict__ counts,
                                                 int* __restrict__ cols) {
  int row = blockIdx.x;
  __shared__ int cnt;
  if (threadIdx.x == 0) cnt = 0;
  __syncthreads();
  const float4* arow = (const float4*)(adj + (size_t)row * N);
  for (int c4 = threadIdx.x; c4 < N / 4; c4 += 256) {
    float4 v = arow[c4];
    int base = c4 * 4;
    if (v.x > 0.f) { int k = atomicAdd(&cnt, 1); if (k < CAP) cols[(size_t)row * CAP + k] = base; }
    if (v.y > 0.f) { int k = atomicAdd(&cnt, 1); if (k < CAP) cols[(size_t)row * CAP + k] = base + 1; }
    if (v.z > 0.f) { int k = atomicAdd(&cnt, 1); if (k < CAP) cols[(size_t)row * CAP + k] = base + 2; }
    if (v.w > 0.f) { int k = atomicAdd(&cnt, 1); if (k < CAP) cols[(size_t)row * CAP + k] = base + 3; }
  }
  __syncthreads();
  if (threadIdx.x == 0) counts[row] = cnt < CAP ? cnt : CAP;
}

// ---------------- K2: f32 tiled GEMM, C[M x 64] = A[M x K] @ B[K x 64] -----
// blockIdx.y selects a (B, C) block pair (used for the 8 heads of layer 1).
__global__ __launch_bounds__(256) void gemm64(const float* __restrict__ A, int lda,
                                              const float* __restrict__ B, size_t bBlock,
                                              float* __restrict__ C, size_t cBlock,
                                              int K) {
  __shared__ float As[16][68];  // padded: A-tile stored transposed, 2-way max on writes
  __shared__ float Bs[16][64];
  const float* Bp = B + (size_t)blockIdx.y * bBlock;
  float* Cp = C + (size_t)blockIdx.y * cBlock;
  int m0 = blockIdx.x * 64;
  int t = threadIdx.x;
  int tx = t & 15, ty = t >> 4;
  int lam = t >> 2;         // 0..63 : A-tile row
  int lak = (t & 3) * 4;    // 0,4,8,12 : A-tile k quad
  int lbk = t >> 4;         // 0..15 : B-tile k
  int lbn = (t & 15) * 4;   // B-tile col quad
  float acc[4][4] = {};
  for (int k0 = 0; k0 < K; k0 += 16) {
    float4 av = *(const float4*)(A + (size_t)(m0 + lam) * lda + k0 + lak);
    float4 bv = *(const float4*)(Bp + (size_t)(k0 + lbk) * 64 + lbn);
    As[lak + 0][lam] = av.x;
    As[lak + 1][lam] = av.y;
    As[lak + 2][lam] = av.z;
    As[lak + 3][lam] = av.w;
    *(float4*)(&Bs[lbk][lbn]) = bv;
    __syncthreads();
#pragma unroll
    for (int k = 0; k < 16; ++k) {
      float4 a = *(const float4*)(&As[k][ty * 4]);
      float4 b = *(const float4*)(&Bs[k][tx * 4]);
      float ar[4] = {a.x, a.y, a.z, a.w};
      float br[4] = {b.x, b.y, b.z, b.w};
#pragma unroll
      for (int i = 0; i < 4; i++)
#pragma unroll
        for (int j = 0; j < 4; j++)
          acc[i][j] = fmaf(ar[i], br[j], acc[i][j]);
    }
    __syncthreads();
  }
#pragma unroll
  for (int i = 0; i < 4; i++) {
    float4 o = {acc[i][0], acc[i][1], acc[i][2], acc[i][3]};
    *(float4*)(Cp + (size_t)(m0 + ty * 4 + i) * 64 + tx * 4) = o;
  }
}

// ---------------- K3: e_src / e_dst (one wave per (head,node)) -------------
__global__ __launch_bounds__(256) void compute_ee(const float* __restrict__ Wh,
                                                  const float* __restrict__ a,
                                                  float* __restrict__ esrc,
                                                  float* __restrict__ edst) {
  int w = (blockIdx.x << 2) + (threadIdx.x >> 6);
  int lane = threadIdx.x & 63;
  int i = w & (N - 1);
  int h = w >> 12;
  float v = Wh[((size_t)h * N + i) * 64 + lane];
  float s = v * a[h * 128 + lane];
  float d = v * a[h * 128 + 64 + lane];
#pragma unroll
  for (int off = 32; off; off >>= 1) {
    s += __shfl_xor(s, off);
    d += __shfl_xor(d, off);
  }
  if (lane == 0) {
    esrc[h * N + i] = s;
    edst[h * N + i] = d;
  }
}

// ---------------- K4: column sums of Wh (fallback for degree-0 rows) -------
__global__ __launch_bounds__(256) void sum_wh(const float* __restrict__ Wh,
                                              float* __restrict__ sumWh) {
  int h = blockIdx.x;
  int d = threadIdx.x & 63;
  int part = threadIdx.x >> 6;
  float s = 0.f;
  for (int i = part; i < N; i += 4)
    s += Wh[((size_t)h * N + i) * 64 + d];
  __shared__ float red[4][64];
  red[part][d] = s;
  __syncthreads();
  if (part == 0)
    sumWh[h * 64 + d] = red[0][d] + red[1][d] + red[2][d] + red[3][d];
}

// ---------------- K5: sparse GAT attention (one wave per (node, head)) -----
// lane = hidden dim. Two passes over neighbors: max, then exp/accumulate.
__global__ __launch_bounds__(256) void gat_attn(const float* __restrict__ Wh,
                                                const float* __restrict__ esrc,
                                                const float* __restrict__ edst,
                                                const int* __restrict__ counts,
                                                const int* __restrict__ cols,
                                                const float* __restrict__ sumWh,
                                                float* __restrict__ out,
                                                int Hlog2, int outStride) {
  int w = (blockIdx.x << 2) + (threadIdx.x >> 6);
  int lane = threadIdx.x & 63;
  int i = w >> Hlog2;
  int h = w & ((1 << Hlog2) - 1);
  int cnt = counts[i];
  const float* WhH = Wh + (size_t)h * N * 64;
  float acc;
  if (cnt == 0) {
    // softmax over all -9e15 logits is uniform 1/N
    acc = sumWh[h * 64 + lane] * (1.0f / N);
  } else {
    const int* cl = cols + (size_t)i * CAP;
    float ei = esrc[h * N + i];
    const float* ed = edst + (size_t)h * N;
    float m = -1e30f;
    for (int k = lane; k < cnt; k += 64) {
      float e = ei + ed[cl[k]];
      e = (e > 0.f) ? e : LRELU_ALPHA * e;
      m = fmaxf(m, e);
    }
#pragma unroll
    for (int off = 32; off; off >>= 1) m = fmaxf(m, __shfl_xor(m, off));
    acc = 0.f;
    float ssum = 0.f;
    for (int k = 0; k < cnt; ++k) {
      int j = cl[k];
      float e = ei + ed[j];
      e = (e > 0.f) ? e : LRELU_ALPHA * e;
      float p = __expf(e - m);
      ssum += p;
      acc = fmaf(p, WhH[(size_t)j * 64 + lane], acc);
    }
    acc /= ssum;
  }
  // ELU (applied after both layers in the reference)
  acc = (acc > 0.f) ? acc : expm1f(acc);
  out[(size_t)i * outStride + h * 64 + lane] = acc;
}

// ---------------- K6: pairwise bilinear scores ------------------------------
__global__ __launch_bounds__(256) void score_k(const float* __restrict__ g,
                                               const float* __restrict__ hf,
                                               const int* __restrict__ p1,
                                               const int* __restrict__ p2,
                                               float* __restrict__ out) {
  int w = (blockIdx.x << 2) + (threadIdx.x >> 6);
  int lane = threadIdx.x & 63;
  int i1 = p1[w], i2 = p2[w];
  float v = g[(size_t)i1 * 64 + lane] * hf[(size_t)i2 * 64 + lane];
#pragma unroll
  for (int off = 32; off; off >>= 1) v += __shfl_xor(v, off);
  if (lane == 0) out[w] = v;
}

extern "C" void kernel_launch(void* const* d_in, const int* in_sizes, int n_in,
                              void* d_out, int out_size, void* d_ws, size_t ws_size,
                              hipStream_t stream) {
  const float* x       = (const float*)d_in[0];
  const float* adj     = (const float*)d_in[1];
  const float* W_heads = (const float*)d_in[2];
  const float* a_heads = (const float*)d_in[3];
  const float* W_out   = (const float*)d_in[4];
  const float* a_out   = (const float*)d_in[5];
  const float* W_score = (const float*)d_in[6];
  const int* p1        = (const int*)d_in[7];
  const int* p2        = (const int*)d_in[8];
  float* out           = (float*)d_out;

  char* ws = (char*)d_ws;
  size_t off = 0;
  auto alloc = [&](size_t bytes) -> void* {
    void* p = ws + off;
    off += (bytes + 255) & ~(size_t)255;
    return p;
  };
  int*   counts = (int*)alloc((size_t)N * 4);
  int*   cols   = (int*)alloc((size_t)N * CAP * 4);
  float* Wh1    = (float*)alloc((size_t)NHEADS * N * 64 * 4);
  float* es1    = (float*)alloc((size_t)NHEADS * N * 4);
  float* ed1    = (float*)alloc((size_t)NHEADS * N * 4);
  float* sum1   = (float*)alloc((size_t)NHEADS * 64 * 4);
  float* h1     = (float*)alloc((size_t)N * 512 * 4);
  float* Wh2    = (float*)alloc((size_t)N * 64 * 4);
  float* es2    = (float*)alloc((size_t)N * 4);
  float* ed2    = (float*)alloc((size_t)N * 4);
  float* sum2   = (float*)alloc((size_t)64 * 4);
  float* hf     = (float*)alloc((size_t)N * 64 * 4);
  float* g      = (float*)alloc((size_t)N * 64 * 4);

  // adjacency -> CSR (shared by both layers)
  build_csr<<<N, 256, 0, stream>>>(adj, counts, cols);

  // ---- layer 1 (8 heads) ----
  gemm64<<<dim3(N / 64, NHEADS), 256, 0, stream>>>(x, NFEAT, W_heads,
                                                   (size_t)NFEAT * 64, Wh1,
                                                   (size_t)N * 64, NFEAT);
  compute_ee<<<NHEADS * N / 4, 256, 0, stream>>>(Wh1, a_heads, es1, ed1);
  sum_wh<<<NHEADS, 256, 0, stream>>>(Wh1, sum1);
  gat_attn<<<NHEADS * N / 4, 256, 0, stream>>>(Wh1, es1, ed1, counts, cols,
                                               sum1, h1, 3, 512);

  // ---- layer 2 (1 head) ----
  gemm64<<<dim3(N / 64, 1), 256, 0, stream>>>(h1, 512, W_out, 0, Wh2, 0, 512);
  compute_ee<<<N / 4, 256, 0, stream>>>(Wh2, a_out, es2, ed2);
  sum_wh<<<1, 256, 0, stream>>>(Wh2, sum2);
  gat_attn<<<N / 4, 256, 0, stream>>>(Wh2, es2, ed2, counts, cols, sum2, hf, 0, 64);

  // ---- pairwise scores ----
  gemm64<<<dim3(N / 64, 1), 256, 0, stream>>>(hf, 64, W_score, 0, g, 0, 64);
  score_k<<<P_PAIRS / 4, 256, 0, stream>>>(g, hf, p1, p2, out);
}

// Round 2
// 239.050 us; speedup vs baseline: 2.7976x; 2.7976x over previous
//
#include <hip/hip_runtime.h>
#include <math.h>

#define N 4096
#define NFEAT 512
#define NHID 64
#define NHEADS 8
#define P_PAIRS 65536
#define CAP 128
#define LRELU_ALPHA 0.2f
#define SUM_SLICES 32  // blocks per head for the column-sum reduction

// ---------------- K1: build CSR from dense adj (one pass over 67 MB) -------
__global__ __launch_bounds__(256) void build_csr(const float* __restrict__ adj,
                                                 int* __restrict__ counts,
                                                 int* __restrict__ cols) {
  int row = blockIdx.x;
  __shared__ int cnt;
  if (threadIdx.x == 0) cnt = 0;
  __syncthreads();
  const float4* arow = (const float4*)(adj + (size_t)row * N);
  for (int c4 = threadIdx.x; c4 < N / 4; c4 += 256) {
    float4 v = arow[c4];
    int base = c4 * 4;
    if (v.x > 0.f) { int k = atomicAdd(&cnt, 1); if (k < CAP) cols[(size_t)row * CAP + k] = base; }
    if (v.y > 0.f) { int k = atomicAdd(&cnt, 1); if (k < CAP) cols[(size_t)row * CAP + k] = base + 1; }
    if (v.z > 0.f) { int k = atomicAdd(&cnt, 1); if (k < CAP) cols[(size_t)row * CAP + k] = base + 2; }
    if (v.w > 0.f) { int k = atomicAdd(&cnt, 1); if (k < CAP) cols[(size_t)row * CAP + k] = base + 3; }
  }
  __syncthreads();
  if (threadIdx.x == 0) counts[row] = cnt < CAP ? cnt : CAP;
}

// ---------------- K2: f32 tiled GEMM, C[M x 64] = A[M x K] @ B[K x 64] -----
// blockIdx.y selects a (B, C) block pair (used for the 8 heads of layer 1).
__global__ __launch_bounds__(256) void gemm64(const float* __restrict__ A, int lda,
                                              const float* __restrict__ B, size_t bBlock,
                                              float* __restrict__ C, size_t cBlock,
                                              int K) {
  __shared__ float As[16][68];  // padded: A-tile stored transposed
  __shared__ float Bs[16][64];
  const float* Bp = B + (size_t)blockIdx.y * bBlock;
  float* Cp = C + (size_t)blockIdx.y * cBlock;
  int m0 = blockIdx.x * 64;
  int t = threadIdx.x;
  int tx = t & 15, ty = t >> 4;
  int lam = t >> 2;         // 0..63 : A-tile row
  int lak = (t & 3) * 4;    // 0,4,8,12 : A-tile k quad
  int lbk = t >> 4;         // 0..15 : B-tile k
  int lbn = (t & 15) * 4;   // B-tile col quad
  float acc[4][4] = {};
  for (int k0 = 0; k0 < K; k0 += 16) {
    float4 av = *(const float4*)(A + (size_t)(m0 + lam) * lda + k0 + lak);
    float4 bv = *(const float4*)(Bp + (size_t)(k0 + lbk) * 64 + lbn);
    As[lak + 0][lam] = av.x;
    As[lak + 1][lam] = av.y;
    As[lak + 2][lam] = av.z;
    As[lak + 3][lam] = av.w;
    *(float4*)(&Bs[lbk][lbn]) = bv;
    __syncthreads();
#pragma unroll
    for (int k = 0; k < 16; ++k) {
      float4 a = *(const float4*)(&As[k][ty * 4]);
      float4 b = *(const float4*)(&Bs[k][tx * 4]);
      float ar[4] = {a.x, a.y, a.z, a.w};
      float br[4] = {b.x, b.y, b.z, b.w};
#pragma unroll
      for (int i = 0; i < 4; i++)
#pragma unroll
        for (int j = 0; j < 4; j++)
          acc[i][j] = fmaf(ar[i], br[j], acc[i][j]);
    }
    __syncthreads();
  }
#pragma unroll
  for (int i = 0; i < 4; i++) {
    float4 o = {acc[i][0], acc[i][1], acc[i][2], acc[i][3]};
    *(float4*)(Cp + (size_t)(m0 + ty * 4 + i) * 64 + tx * 4) = o;
  }
}

// ---------------- K3: e_src / e_dst (one wave per (head,node)) -------------
__global__ __launch_bounds__(256) void compute_ee(const float* __restrict__ Wh,
                                                  const float* __restrict__ a,
                                                  float* __restrict__ esrc,
                                                  float* __restrict__ edst) {
  int w = (blockIdx.x << 2) + (threadIdx.x >> 6);
  int lane = threadIdx.x & 63;
  int i = w & (N - 1);
  int h = w >> 12;
  float v = Wh[((size_t)h * N + i) * 64 + lane];
  float s = v * a[h * 128 + lane];
  float d = v * a[h * 128 + 64 + lane];
#pragma unroll
  for (int off = 32; off; off >>= 1) {
    s += __shfl_xor(s, off);
    d += __shfl_xor(d, off);
  }
  if (lane == 0) {
    esrc[h * N + i] = s;
    edst[h * N + i] = d;
  }
}

// ---------------- K4a: partial column sums of Wh (SUM_SLICES blocks/head) --
__global__ __launch_bounds__(256) void sum_wh_partial(const float* __restrict__ Wh,
                                                      float* __restrict__ partial) {
  int h = blockIdx.x / SUM_SLICES;
  int j = blockIdx.x % SUM_SLICES;
  int d = threadIdx.x & 63;
  int part = threadIdx.x >> 6;
  const int rowsPerSlice = N / SUM_SLICES;  // 128
  int base = j * rowsPerSlice;
  float s = 0.f;
  for (int i = base + part; i < base + rowsPerSlice; i += 4)
    s += Wh[((size_t)h * N + i) * 64 + d];
  __shared__ float red[4][64];
  red[part][d] = s;
  __syncthreads();
  if (part == 0)
    partial[((size_t)h * SUM_SLICES + j) * 64 + d] =
        red[0][d] + red[1][d] + red[2][d] + red[3][d];
}

// ---------------- K4b: fold the partials ----------------------------------
__global__ __launch_bounds__(64) void sum_wh_final(const float* __restrict__ partial,
                                                   float* __restrict__ sumWh) {
  int h = blockIdx.x;
  int d = threadIdx.x;
  float s = 0.f;
#pragma unroll
  for (int j = 0; j < SUM_SLICES; ++j)
    s += partial[((size_t)h * SUM_SLICES + j) * 64 + d];
  sumWh[h * 64 + d] = s;
}

// ---------------- K5: sparse GAT attention (one wave per (node, head)) -----
__global__ __launch_bounds__(256) void gat_attn(const float* __restrict__ Wh,
                                                const float* __restrict__ esrc,
                                                const float* __restrict__ edst,
                                                const int* __restrict__ counts,
                                                const int* __restrict__ cols,
                                                const float* __restrict__ sumWh,
                                                float* __restrict__ out,
                                                int Hlog2, int outStride) {
  int w = (blockIdx.x << 2) + (threadIdx.x >> 6);
  int lane = threadIdx.x & 63;
  int i = w >> Hlog2;
  int h = w & ((1 << Hlog2) - 1);
  int cnt = counts[i];
  const float* WhH = Wh + (size_t)h * N * 64;
  float acc;
  if (cnt == 0) {
    acc = sumWh[h * 64 + lane] * (1.0f / N);  // softmax over uniform NEG row
  } else {
    const int* cl = cols + (size_t)i * CAP;
    float ei = esrc[h * N + i];
    const float* ed = edst + (size_t)h * N;
    float m = -1e30f;
    for (int k = lane; k < cnt; k += 64) {
      float e = ei + ed[cl[k]];
      e = (e > 0.f) ? e : LRELU_ALPHA * e;
      m = fmaxf(m, e);
    }
#pragma unroll
    for (int off = 32; off; off >>= 1) m = fmaxf(m, __shfl_xor(m, off));
    acc = 0.f;
    float ssum = 0.f;
    for (int k = 0; k < cnt; ++k) {
      int j = cl[k];
      float e = ei + ed[j];
      e = (e > 0.f) ? e : LRELU_ALPHA * e;
      float p = __expf(e - m);
      ssum += p;
      acc = fmaf(p, WhH[(size_t)j * 64 + lane], acc);
    }
    acc /= ssum;
  }
  acc = (acc > 0.f) ? acc : expm1f(acc);  // ELU
  out[(size_t)i * outStride + h * 64 + lane] = acc;
}

// ---------------- K6: pairwise bilinear scores ------------------------------
__global__ __launch_bounds__(256) void score_k(const float* __restrict__ g,
                                               const float* __restrict__ hf,
                                               const int* __restrict__ p1,
                                               const int* __restrict__ p2,
                                               float* __restrict__ out) {
  int w = (blockIdx.x << 2) + (threadIdx.x >> 6);
  int lane = threadIdx.x & 63;
  int i1 = p1[w], i2 = p2[w];
  float v = g[(size_t)i1 * 64 + lane] * hf[(size_t)i2 * 64 + lane];
#pragma unroll
  for (int off = 32; off; off >>= 1) v += __shfl_xor(v, off);
  if (lane == 0) out[w] = v;
}

extern "C" void kernel_launch(void* const* d_in, const int* in_sizes, int n_in,
                              void* d_out, int out_size, void* d_ws, size_t ws_size,
                              hipStream_t stream) {
  const float* x       = (const float*)d_in[0];
  const float* adj     = (const float*)d_in[1];
  const float* W_heads = (const float*)d_in[2];
  const float* a_heads = (const float*)d_in[3];
  const float* W_out   = (const float*)d_in[4];
  const float* a_out   = (const float*)d_in[5];
  const float* W_score = (const float*)d_in[6];
  const int* p1        = (const int*)d_in[7];
  const int* p2        = (const int*)d_in[8];
  float* out           = (float*)d_out;

  char* ws = (char*)d_ws;
  size_t off = 0;
  auto alloc = [&](size_t bytes) -> void* {
    void* p = ws + off;
    off += (bytes + 255) & ~(size_t)255;
    return p;
  };
  int*   counts  = (int*)alloc((size_t)N * 4);
  int*   cols    = (int*)alloc((size_t)N * CAP * 4);
  float* Wh1     = (float*)alloc((size_t)NHEADS * N * 64 * 4);
  float* es1     = (float*)alloc((size_t)NHEADS * N * 4);
  float* ed1     = (float*)alloc((size_t)NHEADS * N * 4);
  float* sum1    = (float*)alloc((size_t)NHEADS * 64 * 4);
  float* part1   = (float*)alloc((size_t)NHEADS * SUM_SLICES * 64 * 4);
  float* h1      = (float*)alloc((size_t)N * 512 * 4);
  float* Wh2     = (float*)alloc((size_t)N * 64 * 4);
  float* es2     = (float*)alloc((size_t)N * 4);
  float* ed2     = (float*)alloc((size_t)N * 4);
  float* sum2    = (float*)alloc((size_t)64 * 4);
  float* part2   = (float*)alloc((size_t)SUM_SLICES * 64 * 4);
  float* hf      = (float*)alloc((size_t)N * 64 * 4);
  float* g       = (float*)alloc((size_t)N * 64 * 4);

  // adjacency -> CSR (shared by both layers)
  build_csr<<<N, 256, 0, stream>>>(adj, counts, cols);

  // ---- layer 1 (8 heads) ----
  gemm64<<<dim3(N / 64, NHEADS), 256, 0, stream>>>(x, NFEAT, W_heads,
                                                   (size_t)NFEAT * 64, Wh1,
                                                   (size_t)N * 64, NFEAT);
  compute_ee<<<NHEADS * N / 4, 256, 0, stream>>>(Wh1, a_heads, es1, ed1);
  sum_wh_partial<<<NHEADS * SUM_SLICES, 256, 0, stream>>>(Wh1, part1);
  sum_wh_final<<<NHEADS, 64, 0, stream>>>(part1, sum1);
  gat_attn<<<NHEADS * N / 4, 256, 0, stream>>>(Wh1, es1, ed1, counts, cols,
                                               sum1, h1, 3, 512);

  // ---- layer 2 (1 head) ----
  gemm64<<<dim3(N / 64, 1), 256, 0, stream>>>(h1, 512, W_out, 0, Wh2, 0, 512);
  compute_ee<<<N / 4, 256, 0, stream>>>(Wh2, a_out, es2, ed2);
  sum_wh_partial<<<SUM_SLICES, 256, 0, stream>>>(Wh2, part2);
  sum_wh_final<<<1, 64, 0, stream>>>(part2, sum2);
  gat_attn<<<N / 4, 256, 0, stream>>>(Wh2, es2, ed2, counts, cols, sum2, hf, 0, 64);

  // ---- pairwise scores ----
  gemm64<<<dim3(N / 64, 1), 256, 0, stream>>>(hf, 64, W_score, 0, g, 0, 64);
  score_k<<<P_PAIRS / 4, 256, 0, stream>>>(g, hf, p1, p2, out);
}

// Round 3
// 161.614 us; speedup vs baseline: 4.1381x; 1.4791x over previous
//
#include <hip/hip_runtime.h>
#include <math.h>

#define N 4096
#define NFEAT 512
#define NHID 64
#define NHEADS 8
#define P_PAIRS 65536
#define CAP 128
#define LRELU_ALPHA 0.2f
#define SLICES 32  // row-slices for the column-sum reduction

// ---------------- K1: build CSR from dense adj (one pass over 67 MB) -------
__global__ __launch_bounds__(256) void build_csr(const float* __restrict__ adj,
                                                 int* __restrict__ counts,
                                                 int* __restrict__ cols) {
  int row = blockIdx.x;
  __shared__ int cnt;
  if (threadIdx.x == 0) cnt = 0;
  __syncthreads();
  const float4* arow = (const float4*)(adj + (size_t)row * N);
  for (int c4 = threadIdx.x; c4 < N / 4; c4 += 256) {
    float4 v = arow[c4];
    int base = c4 * 4;
    if (v.x > 0.f) { int k = atomicAdd(&cnt, 1); if (k < CAP) cols[(size_t)row * CAP + k] = base; }
    if (v.y > 0.f) { int k = atomicAdd(&cnt, 1); if (k < CAP) cols[(size_t)row * CAP + k] = base + 1; }
    if (v.z > 0.f) { int k = atomicAdd(&cnt, 1); if (k < CAP) cols[(size_t)row * CAP + k] = base + 2; }
    if (v.w > 0.f) { int k = atomicAdd(&cnt, 1); if (k < CAP) cols[(size_t)row * CAP + k] = base + 3; }
  }
  __syncthreads();
  if (threadIdx.x == 0) counts[row] = cnt < CAP ? cnt : CAP;
}

// ---------------- K2: f32 tiled GEMM, C[M x 64] = A[M x K] @ B[K x 64] -----
// blockIdx.y selects a B block (bBlock elements apart) and a C column offset
// (cOff elements). C has row stride ldc.
__global__ __launch_bounds__(256) void gemm64(const float* __restrict__ A, int lda,
                                              const float* __restrict__ B, size_t bBlock,
                                              float* __restrict__ C, int cOff, int ldc,
                                              int K) {
  __shared__ float As[16][68];  // padded: A-tile stored transposed
  __shared__ float Bs[16][64];
  const float* Bp = B + (size_t)blockIdx.y * bBlock;
  float* Cp = C + (size_t)blockIdx.y * cOff;
  int m0 = blockIdx.x * 64;
  int t = threadIdx.x;
  int tx = t & 15, ty = t >> 4;
  int lam = t >> 2;         // 0..63 : A-tile row
  int lak = (t & 3) * 4;    // 0,4,8,12 : A-tile k quad
  int lbk = t >> 4;         // 0..15 : B-tile k
  int lbn = (t & 15) * 4;   // B-tile col quad
  float acc[4][4] = {};
  for (int k0 = 0; k0 < K; k0 += 16) {
    float4 av = *(const float4*)(A + (size_t)(m0 + lam) * lda + k0 + lak);
    float4 bv = *(const float4*)(Bp + (size_t)(k0 + lbk) * 64 + lbn);
    As[lak + 0][lam] = av.x;
    As[lak + 1][lam] = av.y;
    As[lak + 2][lam] = av.z;
    As[lak + 3][lam] = av.w;
    *(float4*)(&Bs[lbk][lbn]) = bv;
    __syncthreads();
#pragma unroll
    for (int k = 0; k < 16; ++k) {
      float4 a = *(const float4*)(&As[k][ty * 4]);
      float4 b = *(const float4*)(&Bs[k][tx * 4]);
      float ar[4] = {a.x, a.y, a.z, a.w};
      float br[4] = {b.x, b.y, b.z, b.w};
#pragma unroll
      for (int i = 0; i < 4; i++)
#pragma unroll
        for (int j = 0; j < 4; j++)
          acc[i][j] = fmaf(ar[i], br[j], acc[i][j]);
    }
    __syncthreads();
  }
#pragma unroll
  for (int i = 0; i < 4; i++) {
    float4 o = {acc[i][0], acc[i][1], acc[i][2], acc[i][3]};
    *(float4*)(Cp + (size_t)(m0 + ty * 4 + i) * ldc + tx * 4) = o;
  }
}

// ---------------- K3: e_src / e_dst (one wave per (head,node)) -------------
// Wh is [N][ld] with head h occupying columns [h*64, h*64+64).
__global__ __launch_bounds__(256) void compute_ee(const float* __restrict__ Wh, int ld,
                                                  const float* __restrict__ a,
                                                  float* __restrict__ esrc,
                                                  float* __restrict__ edst) {
  int w = (blockIdx.x << 2) + (threadIdx.x >> 6);
  int lane = threadIdx.x & 63;
  int i = w & (N - 1);
  int h = w >> 12;
  float v = Wh[(size_t)i * ld + (h << 6) + lane];
  float s = v * a[h * 128 + lane];
  float d = v * a[h * 128 + 64 + lane];
#pragma unroll
  for (int off = 32; off; off >>= 1) {
    s += __shfl_xor(s, off);
    d += __shfl_xor(d, off);
  }
  if (lane == 0) {
    esrc[h * N + i] = s;
    edst[h * N + i] = d;
  }
}

// ---------------- K4a: partial column sums of M[N][C] ----------------------
__global__ __launch_bounds__(256) void col_sum_partial(const float* __restrict__ M, int C,
                                                       float* __restrict__ partial) {
  int col = blockIdx.x * 64 + (threadIdx.x & 63);
  int part = threadIdx.x >> 6;
  const int rows = N / SLICES;  // 128
  int base = blockIdx.y * rows;
  float s = 0.f;
  for (int r = base + part; r < base + rows; r += 4)
    s += M[(size_t)r * C + col];
  __shared__ float red[4][64];
  red[part][threadIdx.x & 63] = s;
  __syncthreads();
  if (part == 0)
    partial[(size_t)blockIdx.y * C + col] =
        red[0][threadIdx.x] + red[1][threadIdx.x] + red[2][threadIdx.x] + red[3][threadIdx.x];
}

// ---------------- K4b: fold the partials ----------------------------------
__global__ __launch_bounds__(64) void col_sum_final(const float* __restrict__ partial, int C,
                                                    float* __restrict__ out) {
  int col = blockIdx.x * 64 + threadIdx.x;
  float s = 0.f;
#pragma unroll
  for (int j = 0; j < SLICES; ++j)
    s += partial[(size_t)j * C + col];
  out[col] = s;
}

// ---------------- K5a: layer-1 attention, one block (8 waves) per node -----
// Wh interleaved [N][512]; wave h serves head h; neighbor list shared in LDS.
__global__ __launch_bounds__(512) void gat_attn_l1(const float* __restrict__ Wh,
                                                   const float* __restrict__ esrc,
                                                   const float* __restrict__ edst,
                                                   const int* __restrict__ counts,
                                                   const int* __restrict__ cols,
                                                   const float* __restrict__ sumWh,
                                                   float* __restrict__ out) {
  int i = blockIdx.x;
  int tid = threadIdx.x;
  int lane = tid & 63;
  int h = tid >> 6;
  int cnt = counts[i];
  __shared__ int jls[CAP];
  __shared__ float pls[NHEADS][CAP];
  float acc = 0.f;
  if (cnt == 0) {
    acc = sumWh[tid] * (1.0f / N);  // softmax over uniform NEG row
  } else {
    if (tid < cnt) jls[tid] = cols[(size_t)i * CAP + tid];
    __syncthreads();
    // pass 1: lane-parallel e -> p (each lane owns neighbors lane, lane+64)
    float ei = esrc[h * N + i];
    const float* ed = edst + (size_t)h * N;
    float e0 = -1e30f, e1 = -1e30f;
    if (lane < cnt) {
      float e = ei + ed[jls[lane]];
      e0 = (e > 0.f) ? e : LRELU_ALPHA * e;
    }
    if (lane + 64 < cnt) {
      float e = ei + ed[jls[lane + 64]];
      e1 = (e > 0.f) ? e : LRELU_ALPHA * e;
    }
    float m = fmaxf(e0, e1);
#pragma unroll
    for (int off = 32; off; off >>= 1) m = fmaxf(m, __shfl_xor(m, off));
    float p0 = (lane < cnt) ? __expf(e0 - m) : 0.f;
    float p1 = (lane + 64 < cnt) ? __expf(e1 - m) : 0.f;
    float ssum = p0 + p1;
#pragma unroll
    for (int off = 32; off; off >>= 1) ssum += __shfl_xor(ssum, off);
    pls[h][lane] = p0;
    pls[h][lane + 64] = p1;  // own-wave write->read, no barrier needed
    // pass 2: gather-accumulate, 4 loads in flight
    int k = 0;
    for (; k + 4 <= cnt; k += 4) {
      int ja = jls[k + 0], jb = jls[k + 1], jc = jls[k + 2], jd = jls[k + 3];
      float pa = pls[h][k + 0], pb = pls[h][k + 1];
      float pc = pls[h][k + 2], pd = pls[h][k + 3];
      float va = Wh[((size_t)ja << 9) + tid];
      float vb = Wh[((size_t)jb << 9) + tid];
      float vc = Wh[((size_t)jc << 9) + tid];
      float vd = Wh[((size_t)jd << 9) + tid];
      acc = fmaf(pa, va, acc);
      acc = fmaf(pb, vb, acc);
      acc = fmaf(pc, vc, acc);
      acc = fmaf(pd, vd, acc);
    }
    for (; k < cnt; ++k)
      acc = fmaf(pls[h][k], Wh[((size_t)jls[k] << 9) + tid], acc);
    acc /= ssum;
  }
  acc = (acc > 0.f) ? acc : expm1f(acc);  // ELU
  out[((size_t)i << 9) + tid] = acc;
}

// ---------------- K5b: layer-2 attention, one wave per node ----------------
__global__ __launch_bounds__(256) void gat_attn_l2(const float* __restrict__ Wh,
                                                   const float* __restrict__ esrc,
                                                   const float* __restrict__ edst,
                                                   const int* __restrict__ counts,
                                                   const int* __restrict__ cols,
                                                   const float* __restrict__ sumWh,
                                                   float* __restrict__ out) {
  int wv = threadIdx.x >> 6;
  int lane = threadIdx.x & 63;
  int i = (blockIdx.x << 2) + wv;
  int cnt = counts[i];
  __shared__ int jls[4][CAP];
  __shared__ float pls[4][CAP];
  float acc = 0.f;
  if (cnt == 0) {
    acc = sumWh[lane] * (1.0f / N);
  } else {
    const int* cl = cols + (size_t)i * CAP;
    if (lane < cnt) jls[wv][lane] = cl[lane];
    if (lane + 64 < cnt) jls[wv][lane + 64] = cl[lane + 64];
    float ei = esrc[i];
    float e0 = -1e30f, e1 = -1e30f;
    if (lane < cnt) {
      float e = ei + edst[jls[wv][lane]];
      e0 = (e > 0.f) ? e : LRELU_ALPHA * e;
    }
    if (lane + 64 < cnt) {
      float e = ei + edst[jls[wv][lane + 64]];
      e1 = (e > 0.f) ? e : LRELU_ALPHA * e;
    }
    float m = fmaxf(e0, e1);
#pragma unroll
    for (int off = 32; off; off >>= 1) m = fmaxf(m, __shfl_xor(m, off));
    float p0 = (lane < cnt) ? __expf(e0 - m) : 0.f;
    float p1 = (lane + 64 < cnt) ? __expf(e1 - m) : 0.f;
    float ssum = p0 + p1;
#pragma unroll
    for (int off = 32; off; off >>= 1) ssum += __shfl_xor(ssum, off);
    pls[wv][lane] = p0;
    pls[wv][lane + 64] = p1;
    int k = 0;
    for (; k + 4 <= cnt; k += 4) {
      int ja = jls[wv][k + 0], jb = jls[wv][k + 1];
      int jc = jls[wv][k + 2], jd = jls[wv][k + 3];
      float pa = pls[wv][k + 0], pb = pls[wv][k + 1];
      float pc = pls[wv][k + 2], pd = pls[wv][k + 3];
      float va = Wh[((size_t)ja << 6) + lane];
      float vb = Wh[((size_t)jb << 6) + lane];
      float vc = Wh[((size_t)jc << 6) + lane];
      float vd = Wh[((size_t)jd << 6) + lane];
      acc = fmaf(pa, va, acc);
      acc = fmaf(pb, vb, acc);
      acc = fmaf(pc, vc, acc);
      acc = fmaf(pd, vd, acc);
    }
    for (; k < cnt; ++k)
      acc = fmaf(pls[wv][k], Wh[((size_t)jls[wv][k] << 6) + lane], acc);
    acc /= ssum;
  }
  acc = (acc > 0.f) ? acc : expm1f(acc);  // ELU
  out[((size_t)i << 6) + lane] = acc;
}

// ---------------- K6: pairwise bilinear scores ------------------------------
__global__ __launch_bounds__(256) void score_k(const float* __restrict__ g,
                                               const float* __restrict__ hf,
                                               const int* __restrict__ p1,
                                               const int* __restrict__ p2,
                                               float* __restrict__ out) {
  int w = (blockIdx.x << 2) + (threadIdx.x >> 6);
  int lane = threadIdx.x & 63;
  int i1 = p1[w], i2 = p2[w];
  float v = g[(size_t)i1 * 64 + lane] * hf[(size_t)i2 * 64 + lane];
#pragma unroll
  for (int off = 32; off; off >>= 1) v += __shfl_xor(v, off);
  if (lane == 0) out[w] = v;
}

extern "C" void kernel_launch(void* const* d_in, const int* in_sizes, int n_in,
                              void* d_out, int out_size, void* d_ws, size_t ws_size,
                              hipStream_t stream) {
  const float* x       = (const float*)d_in[0];
  const float* adj     = (const float*)d_in[1];
  const float* W_heads = (const float*)d_in[2];
  const float* a_heads = (const float*)d_in[3];
  const float* W_out   = (const float*)d_in[4];
  const float* a_out   = (const float*)d_in[5];
  const float* W_score = (const float*)d_in[6];
  const int* p1        = (const int*)d_in[7];
  const int* p2        = (const int*)d_in[8];
  float* out           = (float*)d_out;

  char* ws = (char*)d_ws;
  size_t off = 0;
  auto alloc = [&](size_t bytes) -> void* {
    void* p = ws + off;
    off += (bytes + 255) & ~(size_t)255;
    return p;
  };
  int*   counts  = (int*)alloc((size_t)N * 4);
  int*   cols    = (int*)alloc((size_t)N * CAP * 4);
  float* Wh1     = (float*)alloc((size_t)N * 512 * 4);   // [N][8*64] interleaved
  float* es1     = (float*)alloc((size_t)NHEADS * N * 4);
  float* ed1     = (float*)alloc((size_t)NHEADS * N * 4);
  float* sum1    = (float*)alloc((size_t)512 * 4);
  float* part1   = (float*)alloc((size_t)SLICES * 512 * 4);
  float* h1      = (float*)alloc((size_t)N * 512 * 4);
  float* Wh2     = (float*)alloc((size_t)N * 64 * 4);
  float* es2     = (float*)alloc((size_t)N * 4);
  float* ed2     = (float*)alloc((size_t)N * 4);
  float* sum2    = (float*)alloc((size_t)64 * 4);
  float* part2   = (float*)alloc((size_t)SLICES * 64 * 4);
  float* hf      = (float*)alloc((size_t)N * 64 * 4);
  float* g       = (float*)alloc((size_t)N * 64 * 4);

  // adjacency -> CSR (shared by both layers)
  build_csr<<<N, 256, 0, stream>>>(adj, counts, cols);

  // ---- layer 1 (8 heads, interleaved Wh1 [N][512]) ----
  gemm64<<<dim3(N / 64, NHEADS), 256, 0, stream>>>(x, NFEAT, W_heads,
                                                   (size_t)NFEAT * 64, Wh1, 64, 512, NFEAT);
  compute_ee<<<NHEADS * N / 4, 256, 0, stream>>>(Wh1, 512, a_heads, es1, ed1);
  col_sum_partial<<<dim3(8, SLICES), 256, 0, stream>>>(Wh1, 512, part1);
  col_sum_final<<<8, 64, 0, stream>>>(part1, 512, sum1);
  gat_attn_l1<<<N, 512, 0, stream>>>(Wh1, es1, ed1, counts, cols, sum1, h1);

  // ---- layer 2 (1 head) ----
  gemm64<<<dim3(N / 64, 1), 256, 0, stream>>>(h1, 512, W_out, 0, Wh2, 0, 64, 512);
  compute_ee<<<N / 4, 256, 0, stream>>>(Wh2, 64, a_out, es2, ed2);
  col_sum_partial<<<dim3(1, SLICES), 256, 0, stream>>>(Wh2, 64, part2);
  col_sum_final<<<1, 64, 0, stream>>>(part2, 64, sum2);
  gat_attn_l2<<<N / 4, 256, 0, stream>>>(Wh2, es2, ed2, counts, cols, sum2, hf);

  // ---- pairwise scores ----
  gemm64<<<dim3(N / 64, 1), 256, 0, stream>>>(hf, 64, W_score, 0, g, 0, 64, 64);
  score_k<<<P_PAIRS / 4, 256, 0, stream>>>(g, hf, p1, p2, out);
}